// Round 1
// baseline (571.652 us; speedup 1.0000x reference)
//
#include <hip/hip_runtime.h>
#include <hip/hip_bf16.h>

#define SLEN 2048
#define NB 4
#define NH 16
#define DM 1024
#define DH 64

typedef __attribute__((ext_vector_type(8))) short bf16x8;
typedef __attribute__((ext_vector_type(8))) unsigned short ushort8;
typedef __attribute__((ext_vector_type(4))) float f32x4;

#define MFMA16(a, b, c) __builtin_amdgcn_mfma_f32_16x16x32_bf16((a), (b), (c), 0, 0, 0)

__device__ __forceinline__ unsigned short f2b(float f) {
    unsigned u = __builtin_bit_cast(unsigned, f);
    u = (u + 0x7FFFu + ((u >> 16) & 1u)) >> 16;
    return (unsigned short)u;
}

// ---------------- weight transpose+cast: fp32 [K][N] -> bf16 [N][K] ----------------
__global__ __launch_bounds__(256) void wtrans(const float* __restrict__ in,
                                              unsigned short* __restrict__ out,
                                              int K, int N) {
    __shared__ float tile[32][33];
    int k0 = blockIdx.y * 32, n0 = blockIdx.x * 32;
    int tx = threadIdx.x & 31, ty = threadIdx.x >> 5;
    for (int i = ty; i < 32; i += 8) tile[i][tx] = in[(size_t)(k0 + i) * N + n0 + tx];
    __syncthreads();
    for (int i = ty; i < 32; i += 8) out[(size_t)(n0 + i) * K + k0 + tx] = f2b(tile[tx][i]);
}

// ---------------- V head-transpose: Vh bf16 [B*S][DM] -> Vt [BH*DH][S] ----------------
__global__ __launch_bounds__(256) void vtrans(const unsigned short* __restrict__ Vh,
                                              unsigned short* __restrict__ Vt) {
    int bh = blockIdx.y;
    int b = bh >> 4, h = bh & 15;
    int s0 = blockIdx.x * 64;
    __shared__ __align__(16) unsigned short tile[64][72];
    int t = threadIdx.x;
    int r = t >> 2, seg = (t & 3) * 16;
    const ushort8* src = (const ushort8*)&Vh[(size_t)(b * SLEN + s0 + r) * DM + h * 64 + seg];
    *(ushort8*)&tile[r][seg] = src[0];
    *(ushort8*)&tile[r][seg + 8] = src[1];
    __syncthreads();
    unsigned short tmp[16];
#pragma unroll
    for (int i = 0; i < 16; i++) tmp[i] = tile[seg + i][r];
    ushort8 o0, o1;
#pragma unroll
    for (int i = 0; i < 8; i++) { o0[i] = tmp[i]; o1[i] = tmp[8 + i]; }
    unsigned short* dst = &Vt[(size_t)(bh * 64 + r) * SLEN + s0 + seg];
    *(ushort8*)dst = o0;
    *(ushort8*)&dst[8] = o1;
}

// ---------------- GEMM: C[M][N] = A[M][K] * Bt[N][K]^T  (bf16 MFMA) ----------------
template <bool A_IS_F32, bool OUT_F32>
__global__ __launch_bounds__(256) void gemm_bt(const void* __restrict__ Ap,
                                               const unsigned short* __restrict__ Bt,
                                               void* __restrict__ Cp,
                                               int M, int N, int K, float scale) {
    __shared__ __align__(16) unsigned short As[128 * 40];
    __shared__ __align__(16) unsigned short Bs[128 * 40];
    int m0 = blockIdx.y * 128, n0 = blockIdx.x * 128;
    int t = threadIdx.x;
    int lane = t & 63, w = t >> 6;
    int wm = (w >> 1) * 64, wn = (w & 1) * 64;
    int lr = lane & 15, lk = (lane >> 4) * 8, lq = (lane >> 4) * 4;
    int row = t >> 1, cb = (t & 1) * 16;
    f32x4 acc[4][4] = {};
    for (int kt = 0; kt < K; kt += 32) {
        __syncthreads();
        if constexpr (A_IS_F32) {
            const float* src = &((const float*)Ap)[(size_t)(m0 + row) * K + kt + cb];
            float4 f0 = ((const float4*)src)[0];
            float4 f1 = ((const float4*)src)[1];
            float4 f2 = ((const float4*)src)[2];
            float4 f3 = ((const float4*)src)[3];
            ushort8 h0 = {f2b(f0.x), f2b(f0.y), f2b(f0.z), f2b(f0.w),
                          f2b(f1.x), f2b(f1.y), f2b(f1.z), f2b(f1.w)};
            ushort8 h1 = {f2b(f2.x), f2b(f2.y), f2b(f2.z), f2b(f2.w),
                          f2b(f3.x), f2b(f3.y), f2b(f3.z), f2b(f3.w)};
            *(ushort8*)&As[row * 40 + cb] = h0;
            *(ushort8*)&As[row * 40 + cb + 8] = h1;
        } else {
            const ushort8* src = (const ushort8*)&((const unsigned short*)Ap)[(size_t)(m0 + row) * K + kt + cb];
            *(ushort8*)&As[row * 40 + cb] = src[0];
            *(ushort8*)&As[row * 40 + cb + 8] = src[1];
        }
        {
            const ushort8* src = (const ushort8*)&Bt[(size_t)(n0 + row) * K + kt + cb];
            *(ushort8*)&Bs[row * 40 + cb] = src[0];
            *(ushort8*)&Bs[row * 40 + cb + 8] = src[1];
        }
        __syncthreads();
        bf16x8 a[4], b[4];
#pragma unroll
        for (int mt = 0; mt < 4; mt++) a[mt] = *(const bf16x8*)&As[(wm + mt * 16 + lr) * 40 + lk];
#pragma unroll
        for (int nt = 0; nt < 4; nt++) b[nt] = *(const bf16x8*)&Bs[(wn + nt * 16 + lr) * 40 + lk];
#pragma unroll
        for (int mt = 0; mt < 4; mt++)
#pragma unroll
            for (int nt = 0; nt < 4; nt++) acc[mt][nt] = MFMA16(a[mt], b[nt], acc[mt][nt]);
    }
#pragma unroll
    for (int mt = 0; mt < 4; mt++)
#pragma unroll
        for (int nt = 0; nt < 4; nt++)
#pragma unroll
            for (int r = 0; r < 4; r++) {
                int rr = m0 + wm + mt * 16 + lq + r;
                int cc = n0 + wn + nt * 16 + lr;
                float val = acc[mt][nt][r] * scale;
                if constexpr (OUT_F32)
                    ((float*)Cp)[(size_t)rr * N + cc] = val;
                else
                    ((unsigned short*)Cp)[(size_t)rr * N + cc] = f2b(val);
            }
}

// ---------------- fused causal attention (writes attn + O) ----------------
// grid: BH * (S/64) blocks of 256. wave w owns 16 q-rows.
__global__ __launch_bounds__(256) void attn_kernel(const unsigned short* __restrict__ Qh,
                                                   const unsigned short* __restrict__ Kh,
                                                   const unsigned short* __restrict__ Vt,
                                                   float* __restrict__ attn_out,
                                                   unsigned short* __restrict__ O) {
    int bx = blockIdx.x;
    int qt = bx & 31, bh = bx >> 5;
    int b = bh >> 4, h = bh & 15;
    int q0 = qt * 64;
    int t = threadIdx.x, lane = t & 63, w = t >> 6;
    int lr = lane & 15, lk = (lane >> 4) * 8, lq = (lane >> 4) * 4;
    __shared__ __align__(16) unsigned short Qs[64 * 72];
    __shared__ __align__(16) unsigned short Ks[64 * 72];
    __shared__ __align__(16) unsigned short Vs[64 * 72];
    __shared__ __align__(16) unsigned short Ps[4][16 * 72];

    int sr = t >> 2, seg = (t & 3) * 16;
    {   // stage Q tile once (Q pre-scaled by 1/32 in projection)
        const ushort8* src = (const ushort8*)&Qh[(size_t)(b * SLEN + q0 + sr) * DM + h * 64 + seg];
        *(ushort8*)&Qs[sr * 72 + seg] = src[0];
        *(ushort8*)&Qs[sr * 72 + seg + 8] = src[1];
    }
    __syncthreads();
    bf16x8 aq0 = *(const bf16x8*)&Qs[(w * 16 + lr) * 72 + lk];
    bf16x8 aq1 = *(const bf16x8*)&Qs[(w * 16 + lr) * 72 + 32 + lk];

    int ntile = qt + 1;
    float rowsum[4] = {0.f, 0.f, 0.f, 0.f};

    // ---- pass 1: row sums of exp(s) ----
    for (int j = 0; j < ntile; j++) {
        __syncthreads();
        {
            const ushort8* src = (const ushort8*)&Kh[(size_t)(b * SLEN + j * 64 + sr) * DM + h * 64 + seg];
            *(ushort8*)&Ks[sr * 72 + seg] = src[0];
            *(ushort8*)&Ks[sr * 72 + seg + 8] = src[1];
        }
        __syncthreads();
#pragma unroll
        for (int nt = 0; nt < 4; nt++) {
            f32x4 acc = {0.f, 0.f, 0.f, 0.f};
            bf16x8 b0 = *(const bf16x8*)&Ks[(nt * 16 + lr) * 72 + lk];
            bf16x8 b1 = *(const bf16x8*)&Ks[(nt * 16 + lr) * 72 + 32 + lk];
            acc = MFMA16(aq0, b0, acc);
            acc = MFMA16(aq1, b1, acc);
            int key = j * 64 + nt * 16 + lr;
#pragma unroll
            for (int r = 0; r < 4; r++) {
                int qrow = q0 + w * 16 + lq + r;
                if (key <= qrow) rowsum[r] += __expf(acc[r]);
            }
        }
    }
#pragma unroll
    for (int r = 0; r < 4; r++)
#pragma unroll
        for (int m = 1; m < 16; m <<= 1) rowsum[r] += __shfl_xor(rowsum[r], m);
    float inv[4];
#pragma unroll
    for (int r = 0; r < 4; r++) inv[r] = 1.f / rowsum[r];

    // ---- pass 2: normalized attn writes + PV ----
    f32x4 acco[4] = {};
    for (int j = 0; j < ntile; j++) {
        __syncthreads();
        {
            const ushort8* src = (const ushort8*)&Kh[(size_t)(b * SLEN + j * 64 + sr) * DM + h * 64 + seg];
            *(ushort8*)&Ks[sr * 72 + seg] = src[0];
            *(ushort8*)&Ks[sr * 72 + seg + 8] = src[1];
            const ushort8* vsrc = (const ushort8*)&Vt[(size_t)(bh * 64 + sr) * SLEN + j * 64 + seg];
            *(ushort8*)&Vs[sr * 72 + seg] = vsrc[0];
            *(ushort8*)&Vs[sr * 72 + seg + 8] = vsrc[1];
        }
        __syncthreads();
#pragma unroll
        for (int nt = 0; nt < 4; nt++) {
            f32x4 acc = {0.f, 0.f, 0.f, 0.f};
            bf16x8 b0 = *(const bf16x8*)&Ks[(nt * 16 + lr) * 72 + lk];
            bf16x8 b1 = *(const bf16x8*)&Ks[(nt * 16 + lr) * 72 + 32 + lk];
            acc = MFMA16(aq0, b0, acc);
            acc = MFMA16(aq1, b1, acc);
            int key = j * 64 + nt * 16 + lr;
#pragma unroll
            for (int r = 0; r < 4; r++) {
                int qrow = q0 + w * 16 + lq + r;
                float p = (key <= qrow) ? __expf(acc[r]) * inv[r] : 0.f;
                attn_out[((size_t)bh * SLEN + qrow) * SLEN + key] = p;
                Ps[w][(lq + r) * 72 + nt * 16 + lr] = f2b(p);
            }
        }
        __syncthreads();
        bf16x8 pa0 = *(const bf16x8*)&Ps[w][lr * 72 + lk];
        bf16x8 pa1 = *(const bf16x8*)&Ps[w][lr * 72 + 32 + lk];
#pragma unroll
        for (int nt = 0; nt < 4; nt++) {
            bf16x8 bv0 = *(const bf16x8*)&Vs[(nt * 16 + lr) * 72 + lk];
            bf16x8 bv1 = *(const bf16x8*)&Vs[(nt * 16 + lr) * 72 + 32 + lk];
            acco[nt] = MFMA16(pa0, bv0, acco[nt]);
            acco[nt] = MFMA16(pa1, bv1, acco[nt]);
        }
    }

    // ---- zero-fill the fully-masked region (keys >= (qt+1)*64) ----
    int kz = (qt + 1) * 64;
    if (kz < SLEN) {
        int n4 = (SLEN - kz) >> 2;
        for (int rr = 0; rr < 16; rr++) {
            int qrow = q0 + w * 16 + rr;
            float4* dst = (float4*)&attn_out[((size_t)bh * SLEN + qrow) * SLEN + kz];
            for (int i = lane; i < n4; i += 64) dst[i] = make_float4(0.f, 0.f, 0.f, 0.f);
        }
    }

    // ---- O epilogue ----
#pragma unroll
    for (int nt = 0; nt < 4; nt++)
#pragma unroll
        for (int r = 0; r < 4; r++) {
            int qrow = q0 + w * 16 + lq + r;
            O[(size_t)(b * SLEN + qrow) * DM + h * 64 + nt * 16 + lr] = f2b(acco[nt][r]);
        }
}

extern "C" void kernel_launch(void* const* d_in, const int* in_sizes, int n_in,
                              void* d_out, int out_size, void* d_ws, size_t ws_size,
                              hipStream_t stream) {
    const float* q = (const float*)d_in[0];
    const float* k = (const float*)d_in[1];
    const float* v = (const float*)d_in[2];
    const float* Wq = (const float*)d_in[4];
    const float* Wk = (const float*)d_in[5];
    const float* Wv = (const float*)d_in[6];
    const float* Wo = (const float*)d_in[7];

    char* ws = (char*)d_ws;
    const size_t WSZ = (size_t)DM * DM;        // 1M elems
    const size_t MSZ = (size_t)NB * SLEN * DM; // 8.4M elems
    unsigned short* WqT = (unsigned short*)ws;
    unsigned short* WkT = WqT + WSZ;
    unsigned short* WvT = WkT + WSZ;
    unsigned short* WoT = WvT + WSZ;
    unsigned short* Qh = WoT + WSZ;
    unsigned short* Kh = Qh + MSZ;
    unsigned short* Vh = Kh + MSZ;
    unsigned short* Vt = Vh + MSZ;
    unsigned short* O  = Vt + MSZ;

    float* out = (float*)d_out;
    float* attn = out + MSZ;

    dim3 tg(32, 32);
    wtrans<<<tg, 256, 0, stream>>>(Wq, WqT, DM, DM);
    wtrans<<<tg, 256, 0, stream>>>(Wk, WkT, DM, DM);
    wtrans<<<tg, 256, 0, stream>>>(Wv, WvT, DM, DM);
    wtrans<<<tg, 256, 0, stream>>>(Wo, WoT, DM, DM);

    dim3 gg(DM / 128, NB * SLEN / 128);  // (8, 64)
    const float qscale = 1.f / 32.f;     // 1/sqrt(H*d_k), exact in bf16
    gemm_bt<true, false><<<gg, 256, 0, stream>>>((const void*)q, WqT, (void*)Qh, NB * SLEN, DM, DM, qscale);
    gemm_bt<true, false><<<gg, 256, 0, stream>>>((const void*)k, WkT, (void*)Kh, NB * SLEN, DM, DM, 1.f);
    gemm_bt<true, false><<<gg, 256, 0, stream>>>((const void*)v, WvT, (void*)Vh, NB * SLEN, DM, DM, 1.f);

    vtrans<<<dim3(SLEN / 64, NB * NH), 256, 0, stream>>>(Vh, Vt);

    attn_kernel<<<NB * NH * (SLEN / 64), 256, 0, stream>>>(Qh, Kh, Vt, attn, O);

    gemm_bt<false, true><<<gg, 256, 0, stream>>>((const void*)O, WoT, d_out, NB * SLEN, DM, DM, 1.f);
}

// Round 2
// 537.358 us; speedup vs baseline: 1.0638x; 1.0638x over previous
//
#include <hip/hip_runtime.h>
#include <hip/hip_bf16.h>

#define SLEN 2048
#define NB 4
#define NH 16
#define DM 1024
#define DH 64

typedef __attribute__((ext_vector_type(8))) short bf16x8;
typedef __attribute__((ext_vector_type(8))) unsigned short ushort8;
typedef __attribute__((ext_vector_type(4))) unsigned short ushort4v;
typedef __attribute__((ext_vector_type(4))) float f32x4;

#define MFMA16(a, b, c) __builtin_amdgcn_mfma_f32_16x16x32_bf16((a), (b), (c), 0, 0, 0)

__device__ __forceinline__ unsigned short f2b(float f) {
    unsigned u = __builtin_bit_cast(unsigned, f);
    u = (u + 0x7FFFu + ((u >> 16) & 1u)) >> 16;
    return (unsigned short)u;
}

__device__ __forceinline__ void gload16(const unsigned short* g, unsigned short* l) {
    __builtin_amdgcn_global_load_lds((const __attribute__((address_space(1))) unsigned int*)g,
                                     (__attribute__((address_space(3))) unsigned int*)l,
                                     16, 0, 0);
}

// ---------------- fp32 -> bf16 cast (vectorized) ----------------
__global__ __launch_bounds__(256) void castf2b(const float* __restrict__ in,
                                               unsigned short* __restrict__ out, int n8) {
    int stride = gridDim.x * 256;
    for (int i = blockIdx.x * 256 + threadIdx.x; i < n8; i += stride) {
        float4 a = ((const float4*)in)[2 * i];
        float4 b = ((const float4*)in)[2 * i + 1];
        ushort8 h = {f2b(a.x), f2b(a.y), f2b(a.z), f2b(a.w),
                     f2b(b.x), f2b(b.y), f2b(b.z), f2b(b.w)};
        ((ushort8*)out)[i] = h;
    }
}

// ---------------- weight transpose+cast: fp32 [K][N] -> bf16 [N][K], scaled ----------------
__global__ __launch_bounds__(256) void wtrans(const float* __restrict__ in,
                                              unsigned short* __restrict__ out,
                                              int K, int N, float scale) {
    __shared__ float tile[32][33];
    int k0 = blockIdx.y * 32, n0 = blockIdx.x * 32;
    int tx = threadIdx.x & 31, ty = threadIdx.x >> 5;
    for (int i = ty; i < 32; i += 8) tile[i][tx] = in[(size_t)(k0 + i) * N + n0 + tx];
    __syncthreads();
    for (int i = ty; i < 32; i += 8) out[(size_t)(n0 + i) * K + k0 + tx] = f2b(tile[tx][i] * scale);
}

// ---------------- V head-transpose: Vh bf16 [B*S][DM] -> Vt [BH*DH][S] ----------------
__global__ __launch_bounds__(256) void vtrans(const unsigned short* __restrict__ Vh,
                                              unsigned short* __restrict__ Vt) {
    int bh = blockIdx.y;
    int b = bh >> 4, h = bh & 15;
    int s0 = blockIdx.x * 64;
    __shared__ __align__(16) unsigned short tile[64][72];
    int t = threadIdx.x;
    int r = t >> 2, seg = (t & 3) * 16;
    const ushort8* src = (const ushort8*)&Vh[(size_t)(b * SLEN + s0 + r) * DM + h * 64 + seg];
    *(ushort8*)&tile[r][seg] = src[0];
    *(ushort8*)&tile[r][seg + 8] = src[1];
    __syncthreads();
    unsigned short tmp[16];
#pragma unroll
    for (int i = 0; i < 16; i++) tmp[i] = tile[seg + i][r];
    ushort8 o0, o1;
#pragma unroll
    for (int i = 0; i < 8; i++) { o0[i] = tmp[i]; o1[i] = tmp[8 + i]; }
    unsigned short* dst = &Vt[(size_t)(bh * 64 + r) * SLEN + s0 + seg];
    *(ushort8*)dst = o0;
    *(ushort8*)&dst[8] = o1;
}

// ---------------- GEMM (m97 structure): C[M][N] = A[M][K] * Bt[N][K]^T ----------------
// A,Bt bf16; 128x128 tile, BK=64, global_load_lds staging, linear LDS.
template <bool OUT_F32>
__global__ __launch_bounds__(256) void gemm_lds(const unsigned short* __restrict__ A,
                                                const unsigned short* __restrict__ Bt,
                                                void* __restrict__ Cp,
                                                int M, int N, int K) {
    __shared__ __align__(16) unsigned short As[128 * 64];
    __shared__ __align__(16) unsigned short Bs[128 * 64];
    int m0 = blockIdx.y * 128, n0 = blockIdx.x * 128;
    int t = threadIdx.x, lane = t & 63, w = t >> 6;
    int wm = (w >> 1) * 64, wn = (w & 1) * 64;
    int lr = lane & 15, hi = lane >> 4, lk = hi * 8, lq = hi * 4;
    int srow = w * 8 + (lane >> 3);     // + c*32
    int scol = (lane & 7) * 8;
    f32x4 acc[4][4] = {};
    for (int kt = 0; kt < K; kt += 64) {
        __syncthreads();
#pragma unroll
        for (int c = 0; c < 4; c++) {
            int row = c * 32 + srow;
            gload16(&A[(size_t)(m0 + row) * K + kt + scol], &As[(c * 4 + w) * 512]);
            gload16(&Bt[(size_t)(n0 + row) * K + kt + scol], &Bs[(c * 4 + w) * 512]);
        }
        __syncthreads();
#pragma unroll
        for (int ks = 0; ks < 2; ks++) {
            bf16x8 a[4], b[4];
#pragma unroll
            for (int mt = 0; mt < 4; mt++) a[mt] = *(const bf16x8*)&As[(wm + mt * 16 + lr) * 64 + ks * 32 + lk];
#pragma unroll
            for (int nt = 0; nt < 4; nt++) b[nt] = *(const bf16x8*)&Bs[(wn + nt * 16 + lr) * 64 + ks * 32 + lk];
#pragma unroll
            for (int mt = 0; mt < 4; mt++)
#pragma unroll
                for (int nt = 0; nt < 4; nt++) acc[mt][nt] = MFMA16(a[mt], b[nt], acc[mt][nt]);
        }
    }
#pragma unroll
    for (int mt = 0; mt < 4; mt++)
#pragma unroll
        for (int nt = 0; nt < 4; nt++)
#pragma unroll
            for (int r = 0; r < 4; r++) {
                int rr = m0 + wm + mt * 16 + lq + r;
                int cc = n0 + wn + nt * 16 + lr;
                if constexpr (OUT_F32)
                    ((float*)Cp)[(size_t)rr * N + cc] = acc[mt][nt][r];
                else
                    ((unsigned short*)Cp)[(size_t)rr * N + cc] = f2b(acc[mt][nt][r]);
            }
}

// ---------------- fused causal attention (writes attn + O) ----------------
// Swapped QK^T: acc = mfma(K_frag, Q_frag) -> lane holds 4 CONSECUTIVE keys of one q-row
// => float4 attn stores, scalar rowsum.
__global__ __launch_bounds__(256) void attn_kernel(const unsigned short* __restrict__ Qh,
                                                   const unsigned short* __restrict__ Kh,
                                                   const unsigned short* __restrict__ Vt,
                                                   float* __restrict__ attn_out,
                                                   unsigned short* __restrict__ O) {
    int bx = blockIdx.x;
    int qt = bx & 31, bh = bx >> 5;
    int b = bh >> 4, h = bh & 15;
    int q0 = qt * 64;
    int t = threadIdx.x, lane = t & 63, w = t >> 6;
    int lr = lane & 15, hi = lane >> 4, lk = hi * 8, lq = hi * 4;
    __shared__ __align__(16) unsigned short Qs[64 * 72];
    __shared__ __align__(16) unsigned short Ks[64 * 72];
    __shared__ __align__(16) unsigned short Vs[64 * 72];
    __shared__ __align__(16) unsigned short Ps[4][16 * 72];

    int sr = t >> 2, seg = (t & 3) * 16;
    {   // stage Q tile once (scale folded into Wq)
        const ushort8* src = (const ushort8*)&Qh[(size_t)(b * SLEN + q0 + sr) * DM + h * 64 + seg];
        *(ushort8*)&Qs[sr * 72 + seg] = src[0];
        *(ushort8*)&Qs[sr * 72 + seg + 8] = src[1];
    }
    __syncthreads();
    bf16x8 aq0 = *(const bf16x8*)&Qs[(w * 16 + lr) * 72 + lk];
    bf16x8 aq1 = *(const bf16x8*)&Qs[(w * 16 + lr) * 72 + 32 + lk];

    int qrow = q0 + w * 16 + lr;     // q-row this lane owns in QK/store phase
    int ntile = qt + 1;
    float rowsum = 0.f;

    // ---- pass 1: row sums of exp(s) ----
    for (int j = 0; j < ntile; j++) {
        __syncthreads();
        {
            const ushort8* src = (const ushort8*)&Kh[(size_t)(b * SLEN + j * 64 + sr) * DM + h * 64 + seg];
            *(ushort8*)&Ks[sr * 72 + seg] = src[0];
            *(ushort8*)&Ks[sr * 72 + seg + 8] = src[1];
        }
        __syncthreads();
#pragma unroll
        for (int nt = 0; nt < 4; nt++) {
            f32x4 acc = {0.f, 0.f, 0.f, 0.f};
            bf16x8 b0 = *(const bf16x8*)&Ks[(nt * 16 + lr) * 72 + lk];
            bf16x8 b1 = *(const bf16x8*)&Ks[(nt * 16 + lr) * 72 + 32 + lk];
            acc = MFMA16(b0, aq0, acc);   // swapped: rows=keys, cols=q
            acc = MFMA16(b1, aq1, acc);
#pragma unroll
            for (int r = 0; r < 4; r++) {
                int key = j * 64 + nt * 16 + lq + r;
                if (key <= qrow) rowsum += __expf(acc[r]);
            }
        }
    }
    rowsum += __shfl_xor(rowsum, 16);
    rowsum += __shfl_xor(rowsum, 32);
    float inv = 1.f / rowsum;

    // ---- pass 2: normalized attn writes (float4) + PV ----
    f32x4 acco[4] = {};
    for (int j = 0; j < ntile; j++) {
        __syncthreads();
        {
            const ushort8* src = (const ushort8*)&Kh[(size_t)(b * SLEN + j * 64 + sr) * DM + h * 64 + seg];
            *(ushort8*)&Ks[sr * 72 + seg] = src[0];
            *(ushort8*)&Ks[sr * 72 + seg + 8] = src[1];
            const ushort8* vsrc = (const ushort8*)&Vt[(size_t)(bh * 64 + sr) * SLEN + j * 64 + seg];
            *(ushort8*)&Vs[sr * 72 + seg] = vsrc[0];
            *(ushort8*)&Vs[sr * 72 + seg + 8] = vsrc[1];
        }
        __syncthreads();
#pragma unroll
        for (int nt = 0; nt < 4; nt++) {
            f32x4 acc = {0.f, 0.f, 0.f, 0.f};
            bf16x8 b0 = *(const bf16x8*)&Ks[(nt * 16 + lr) * 72 + lk];
            bf16x8 b1 = *(const bf16x8*)&Ks[(nt * 16 + lr) * 72 + 32 + lk];
            acc = MFMA16(b0, aq0, acc);
            acc = MFMA16(b1, aq1, acc);
            f32x4 pv;
            ushort4v pb;
#pragma unroll
            for (int r = 0; r < 4; r++) {
                int key = j * 64 + nt * 16 + lq + r;
                float p = (key <= qrow) ? __expf(acc[r]) * inv : 0.f;
                pv[r] = p;
                pb[r] = f2b(p);
            }
            *(f32x4*)&attn_out[((size_t)bh * SLEN + qrow) * SLEN + j * 64 + nt * 16 + lq] = pv;
            *(ushort4v*)&Ps[w][lr * 72 + nt * 16 + lq] = pb;
        }
        __syncthreads();
        bf16x8 pa0 = *(const bf16x8*)&Ps[w][lr * 72 + lk];
        bf16x8 pa1 = *(const bf16x8*)&Ps[w][lr * 72 + 32 + lk];
#pragma unroll
        for (int nt = 0; nt < 4; nt++) {
            bf16x8 bv0 = *(const bf16x8*)&Vs[(nt * 16 + lr) * 72 + lk];
            bf16x8 bv1 = *(const bf16x8*)&Vs[(nt * 16 + lr) * 72 + 32 + lk];
            acco[nt] = MFMA16(pa0, bv0, acco[nt]);
            acco[nt] = MFMA16(pa1, bv1, acco[nt]);
        }
    }

    // ---- zero-fill the fully-masked region (keys >= (qt+1)*64) ----
    int kz = (qt + 1) * 64;
    if (kz < SLEN) {
        int n4 = (SLEN - kz) >> 2;
        for (int rr = 0; rr < 16; rr++) {
            int qr = q0 + w * 16 + rr;
            float4* dst = (float4*)&attn_out[((size_t)bh * SLEN + qr) * SLEN + kz];
            for (int i = lane; i < n4; i += 64) dst[i] = make_float4(0.f, 0.f, 0.f, 0.f);
        }
    }

    // ---- O epilogue (acco layout: row=q=lq+r, col=d=lr) ----
#pragma unroll
    for (int nt = 0; nt < 4; nt++)
#pragma unroll
        for (int r = 0; r < 4; r++) {
            int qr = q0 + w * 16 + lq + r;
            O[(size_t)(b * SLEN + qr) * DM + h * 64 + nt * 16 + lr] = f2b(acco[nt][r]);
        }
}

extern "C" void kernel_launch(void* const* d_in, const int* in_sizes, int n_in,
                              void* d_out, int out_size, void* d_ws, size_t ws_size,
                              hipStream_t stream) {
    const float* q = (const float*)d_in[0];
    const float* k = (const float*)d_in[1];
    const float* v = (const float*)d_in[2];
    const float* Wq = (const float*)d_in[4];
    const float* Wk = (const float*)d_in[5];
    const float* Wv = (const float*)d_in[6];
    const float* Wo = (const float*)d_in[7];

    const size_t WSZ = (size_t)DM * DM;        // 1M elems
    const size_t MSZ = (size_t)NB * SLEN * DM; // 8.4M elems

    // workspace: weights + Qh,Kh,Vt,O  (75 MB)
    unsigned short* WqT = (unsigned short*)d_ws;
    unsigned short* WkT = WqT + WSZ;
    unsigned short* WvT = WkT + WSZ;
    unsigned short* WoT = WvT + WSZ;
    unsigned short* Qh = WoT + WSZ;
    unsigned short* Kh = Qh + MSZ;
    unsigned short* Vt = Kh + MSZ;
    unsigned short* O  = Vt + MSZ;

    float* out = (float*)d_out;
    float* attn = out + MSZ;
    // scratch inside d_out's attn region (dead before attn_kernel writes it)
    unsigned short* Cbuf = (unsigned short*)attn;        // bf16 cast buffer (16.8 MB)
    unsigned short* Vh   = Cbuf + MSZ;                   // V projection result (16.8 MB)

    dim3 tg(32, 32);
    wtrans<<<tg, 256, 0, stream>>>(Wq, WqT, DM, DM, 1.f / 32.f);  // fold 1/sqrt(H*dk)
    wtrans<<<tg, 256, 0, stream>>>(Wk, WkT, DM, DM, 1.f);
    wtrans<<<tg, 256, 0, stream>>>(Wv, WvT, DM, DM, 1.f);
    wtrans<<<tg, 256, 0, stream>>>(Wo, WoT, DM, DM, 1.f);

    const int n8 = (int)(MSZ / 8);
    dim3 gg(DM / 128, NB * SLEN / 128);  // (8, 64)

    castf2b<<<2048, 256, 0, stream>>>(q, Cbuf, n8);
    gemm_lds<false><<<gg, 256, 0, stream>>>(Cbuf, WqT, (void*)Qh, NB * SLEN, DM, DM);
    castf2b<<<2048, 256, 0, stream>>>(k, Cbuf, n8);
    gemm_lds<false><<<gg, 256, 0, stream>>>(Cbuf, WkT, (void*)Kh, NB * SLEN, DM, DM);
    castf2b<<<2048, 256, 0, stream>>>(v, Cbuf, n8);
    gemm_lds<false><<<gg, 256, 0, stream>>>(Cbuf, WvT, (void*)Vh, NB * SLEN, DM, DM);

    vtrans<<<dim3(SLEN / 64, NB * NH), 256, 0, stream>>>(Vh, Vt);

    attn_kernel<<<NB * NH * (SLEN / 64), 256, 0, stream>>>(Qh, Kh, Vt, attn, O);

    gemm_lds<true><<<gg, 256, 0, stream>>>(O, WoT, d_out, NB * SLEN, DM, DM);
}